// Round 8
// baseline (569.431 us; speedup 1.0000x reference)
//
#include <hip/hip_runtime.h>
#include <hip/hip_bf16.h>

typedef _Float16 f16;
typedef f16 f16x4 __attribute__((ext_vector_type(4)));
typedef f16 f16x8 __attribute__((ext_vector_type(8)));
typedef __fp16 h16x2 __attribute__((ext_vector_type(2)));
typedef __fp16 h16x4 __attribute__((ext_vector_type(4)));
typedef float f32x4 __attribute__((ext_vector_type(4)));
typedef float f32x16 __attribute__((ext_vector_type(16)));

#define MT 64           // points per block; 4 waves = 2 pairs; ~180 total regs -> 2 waves/SIMD,
                        // 2 blocks/CU (independent barrier domains)
#define INV2PI 0.15915494309189535f

// ---------------- prep: fragment-major Wt (unchanged, proven) ----------------
// wt layout: frag[(layer*8 + wcblk)*16 + kblk][lane][8]  (1 KB per frag, lane-major)
// A[i=lane&31][k = kblk*16 + (lane>>5)*8 + j] = wh[layer][k][wcblk*32 + (lane&31)]
__global__ __launch_bounds__(64)
void prep_wt(const float* __restrict__ wh, f16* __restrict__ wt) {
    const int b = blockIdx.x;                 // 512 = layer(4) x wcblk(8) x kblk(16)
    const int layer = b >> 7, wcblk = (b >> 4) & 7, kblk = b & 15;
    const int lane = threadIdx.x;
    const int l31 = lane & 31, lh = lane >> 5;
    const float* src = wh + layer * 65536 + (kblk * 16 + lh * 8) * 256 + wcblk * 32 + l31;
    f16x8 v;
#pragma unroll
    for (int j = 0; j < 8; j++) v[j] = (f16)src[j * 256];   // 128B-coalesced per half-wave
    *(f16x8*)(wt + b * 512 + lane * 8) = v;                  // 1KB coalesced store
}

__device__ inline f16x4 pk4(float z0, float z1, float z2, float z3) {
    h16x2 a = __builtin_amdgcn_cvt_pkrtz(z0, z1);
    h16x2 b = __builtin_amdgcn_cvt_pkrtz(z2, z3);
    h16x4 r = __builtin_shufflevector(a, b, 0, 1, 2, 3);
    return __builtin_bit_cast(f16x4, r);
}

// D-layout -> B-frag-layout mapping (verified by derivation, checked by harness):
// acc block cb holds ch = 32*cb + 8g + 4lh + jj at reg g*4+jj, lane-half lh.
// B-frag kblk: lane (pt, LH) holds k = 16*kblk + 8*LH + j'.
// quad (g,lh) -> frag 2*cb+(g>>1), elem-lane (g&1)*32 + l31, byte-half lh.
__global__ __launch_bounds__(256, 2)
void siren_fused(const float* __restrict__ coords,
                 const float* __restrict__ ow1, const float* __restrict__ ob1,
                 const float* __restrict__ ow2, const float* __restrict__ ob2,
                 const float* __restrict__ w0, const float* __restrict__ b0,
                 const f16* __restrict__ wt,    // fragment-major, see prep_wt
                 const float* __restrict__ bh,  // [4][256]
                 const float* __restrict__ wf,  // [256]
                 const float* __restrict__ bf,  // [1]
                 float* __restrict__ out) {
    // exchange buffers: [dbuf][pair][16 frags x 512 f16] = 64 KB; ONE barrier per layer
    __shared__ __align__(16) f16 XB[2][2][8192];
    __shared__ float om_rev[MT];

    const int t = threadIdx.x;
    const long base_pt = (long)blockIdx.x * MT;
    const int lane = t & 63;
    const int wave = t >> 6;      // 4 waves = 2 pairs x 2 subs
    const int p = wave >> 1;      // pair: owns points [p*32, p*32+32)
    const int s = wave & 1;       // sub: owns ch [s*128, s*128+128)
    const int l31 = lane & 31;    // point within pair
    const int lh = lane >> 5;     // lane half (k-sub of fragment)

    // ---- omega predictor: 4 threads/point, shfl-reduced ----
    {
        const int pt = t >> 2, q = t & 3;
        f32x4 c = *(const f32x4*)(coords + (base_pt + pt) * 4);
        float z2p = 0.f;
#pragma unroll
        for (int jj = 0; jj < 16; jj++) {
            const int j = q * 16 + jj;
            float z = ob1[j] + c[0] * ow1[j] + c[1] * ow1[64 + j] + c[2] * ow1[128 + j] + c[3] * ow1[192 + j];
            z2p += fmaxf(z, 0.f) * ow2[j];
        }
        z2p += __shfl_xor(z2p, 1, 64);
        z2p += __shfl_xor(z2p, 2, 64);
        if (q == 0) {
            const float sig = 1.f / (1.f + __expf(-(z2p + ob2[0])));
            om_rev[pt] = (10.f + 90.f * sig) * INV2PI;
        }
    }
    __syncthreads();

    const float orv = om_rev[p * 32 + l31];

    // ---- layer 0 (K=4, fp32): each lane computes its 64 D-position channels,
    //      packs to f16 quads, writes XB[0] directly in B-frag layout ----
    {
        f32x4 c = *(const f32x4*)(coords + (base_pt + p * 32 + l31) * 4);
        f16* const xbw = &XB[0][p][0];
#pragma unroll
        for (int b = 0; b < 4; b++) {
            const int cb = 4 * s + b;
#pragma unroll
            for (int g = 0; g < 4; g++) {
                const int ch = 32 * cb + 8 * g + 4 * lh;
                f32x4 wv0 = *(const f32x4*)(w0 + 0 * 256 + ch);
                f32x4 wv1 = *(const f32x4*)(w0 + 1 * 256 + ch);
                f32x4 wv2 = *(const f32x4*)(w0 + 2 * 256 + ch);
                f32x4 wv3 = *(const f32x4*)(w0 + 3 * 256 + ch);
                f32x4 bv  = *(const f32x4*)(b0 + ch);
                float z[4];
#pragma unroll
                for (int j = 0; j < 4; j++) {
                    float zz = bv[j] + c[0] * wv0[j] + c[1] * wv1[j] + c[2] * wv2[j] + c[3] * wv3[j];
                    z[j] = __builtin_amdgcn_sinf(orv * zz);
                }
                *(f16x4*)&xbw[(2 * cb + (g >> 1)) * 512 + ((g & 1) * 32 + l31) * 8 + lh * 4]
                    = pk4(z[0], z[1], z[2], z[3]);
            }
        }
    }
    __syncthreads();

    // ---- hidden layers: wave computes 128 ch x 32 pts over full K=256.
    //      B register-resident (16 frags, 64 VGPR); inner loop = 4 MFMA + 4 global
    //      A-ring loads, ZERO LDS ops. One barrier per layer (dbuf exchange). ----
#pragma unroll 1
    for (int layer = 0; layer < 4; layer++) {
        const int cur = layer & 1;

        // load this layer's B frags: 16 x ds_read_b128, linear (conflict-free)
        f16x8 bfr[16];
        const f16* xbr = &XB[cur][p][0] + lane * 8;
#pragma unroll
        for (int k = 0; k < 16; k++) bfr[k] = *(const f16x8*)(xbr + k * 512);

        // acc init = bias (broadcast loads, L1-resident)
        f32x16 acc[4];
#pragma unroll
        for (int b = 0; b < 4; b++) {
#pragma unroll
            for (int g = 0; g < 4; g++) {
                f32x4 bb = *(const f32x4*)(bh + layer * 256 + 32 * (4 * s + b) + 8 * g + 4 * lh);
#pragma unroll
                for (int j = 0; j < 4; j++) acc[b][g * 4 + j] = bb[j];
            }
        }

        // A ring, depth 2: 4 ch-blocks per slot
        const f16* af = wt + ((layer * 8 + 4 * s) * 16) * 512 + lane * 8;
        f16x8 aA[2][4];
#pragma unroll
        for (int d = 0; d < 2; d++)
#pragma unroll
            for (int b = 0; b < 4; b++)
                aA[d][b] = *(const f16x8*)(af + b * 8192 + d * 512);

        __builtin_amdgcn_s_setprio(1);
#pragma unroll
        for (int kb = 0; kb < 16; kb++) {
            const int sl = kb & 1;                  // static under full unroll
            acc[0] = __builtin_amdgcn_mfma_f32_32x32x16_f16(aA[sl][0], bfr[kb], acc[0], 0, 0, 0);
            acc[1] = __builtin_amdgcn_mfma_f32_32x32x16_f16(aA[sl][1], bfr[kb], acc[1], 0, 0, 0);
            acc[2] = __builtin_amdgcn_mfma_f32_32x32x16_f16(aA[sl][2], bfr[kb], acc[2], 0, 0, 0);
            acc[3] = __builtin_amdgcn_mfma_f32_32x32x16_f16(aA[sl][3], bfr[kb], acc[3], 0, 0, 0);
            if (kb + 2 < 16) {                      // refill ring 2 iters ahead
                aA[sl][0] = *(const f16x8*)(af + 0 * 8192 + (kb + 2) * 512);
                aA[sl][1] = *(const f16x8*)(af + 1 * 8192 + (kb + 2) * 512);
                aA[sl][2] = *(const f16x8*)(af + 2 * 8192 + (kb + 2) * 512);
                aA[sl][3] = *(const f16x8*)(af + 3 * 8192 + (kb + 2) * 512);
            }
        }
        __builtin_amdgcn_s_setprio(0);

        // epilogue: sin + pack + scatter to XB[cur^1] in B-frag layout (16 x 8B writes)
        f16* const xbw = &XB[cur ^ 1][p][0];
#pragma unroll
        for (int b = 0; b < 4; b++) {
            const int cb = 4 * s + b;
#pragma unroll
            for (int g = 0; g < 4; g++) {
                float z[4];
#pragma unroll
                for (int j = 0; j < 4; j++)
                    z[j] = __builtin_amdgcn_sinf(orv * acc[b][g * 4 + j]);
                *(f16x4*)&xbw[(2 * cb + (g >> 1)) * 512 + ((g & 1) * 32 + l31) * 8 + lh * 4]
                    = pk4(z[0], z[1], z[2], z[3]);
            }
        }
        __syncthreads();   // next layer may read XB[cur^1]
    }

    // ---- final layer: out = X @ wf + bf. XB[0] holds X4 in frag layout:
    //      lane (pt,lh) holds k = 16*kblk + 8*lh + j across 16 frags (128 k's);
    //      shfl_xor(32) merges lane halves. Both subs duplicate (cheap). ----
    {
        const f16* xbr = &XB[0][p][0] + lane * 8;
        float ssum = 0.f;
#pragma unroll
        for (int k = 0; k < 16; k++) {
            f16x8 xv = *(const f16x8*)(xbr + k * 512);
            f32x4 wlo = *(const f32x4*)(wf + 16 * k + 8 * lh);
            f32x4 whi = *(const f32x4*)(wf + 16 * k + 8 * lh + 4);
            ssum += (float)xv[0] * wlo[0] + (float)xv[1] * wlo[1]
                  + (float)xv[2] * wlo[2] + (float)xv[3] * wlo[3]
                  + (float)xv[4] * whi[0] + (float)xv[5] * whi[1]
                  + (float)xv[6] * whi[2] + (float)xv[7] * whi[3];
        }
        ssum += __shfl_xor(ssum, 32, 64);
        if (s == 0 && lh == 0) out[base_pt + p * 32 + l31] = ssum + bf[0];
    }
}

extern "C" void kernel_launch(void* const* d_in, const int* in_sizes, int n_in,
                              void* d_out, int out_size, void* d_ws, size_t ws_size,
                              hipStream_t stream) {
    (void)in_sizes; (void)n_in; (void)out_size; (void)ws_size;
    const float* coords = (const float*)d_in[0];
    const float* ow1 = (const float*)d_in[1];
    const float* ob1 = (const float*)d_in[2];
    const float* ow2 = (const float*)d_in[3];
    const float* ob2 = (const float*)d_in[4];
    const float* w0  = (const float*)d_in[5];
    const float* b0  = (const float*)d_in[6];
    const float* wh  = (const float*)d_in[7];
    const float* bh  = (const float*)d_in[8];
    const float* wf  = (const float*)d_in[9];
    const float* bf  = (const float*)d_in[10];
    float* out = (float*)d_out;
    f16* wt = (f16*)d_ws;   // 512 frags * 1KB = 512 KB (L2-resident)

    prep_wt<<<512, 64, 0, stream>>>(wh, wt);
    siren_fused<<<524288 / MT, 256, 0, stream>>>(coords, ow1, ob1, ow2, ob2,
                                                 w0, b0, wt, bh, wf, bf, out);
}